// Round 12
// baseline (4595.634 us; speedup 1.0000x reference)
//
#include <hip/hip_runtime.h>

// LSTMClassification: B=64, T=512, IN=128, H=512, 2 layers + FC(512->1)
// Round 12 = R9 champion body + FULL intra-XCD exchange (both layers):
//   plain (write-through) stores + plain loads with buffer_inv sc0 (per-CU
//   L1-only invalidate -- NOT the L2-writeback that killed round 1). R11's
//   passing probe PROVED plain-store -> XCD-L2 -> other-CU plain-load works;
//   the L1-staleness hole on re-read addresses (flags, parity) is closed by
//   inv: after inv, any fill comes from L2 which is always fresh same-XCD.
//   Chain/step: drain(L2 ack) + plain flag + inv-poll detect + plain load
//   ~= 0.5us, vs champion's 3.5 MALL RTs (6.1us measured).
// Inter-layer (cross-XCD) stays AGENT: L0 dual-stores h0_all[t] (plain+agent,
//   same value -> line-consistent), flB=t attested FREE by vmcnt in-order
//   completion at step t's vmcnt(1); L1 register-prefetches h0[t+1] gated by
//   a register-cached flB (polled only when cache insufficient -- amortized).
// Safety: ALL-PAIRS probe per layer (each WG inv+plain-reads all 64 same-layer
//   producers' nonce'd values; nonce from clock64 so replays can't false-pass;
//   128 votes AND'ed via proven AGENT ops; any failure -> BOTH layers run the
//   exact R9 champion protocol). Placement is frozen for the dispatch
//   (persistent blocks), so a passing probe is valid for the whole run.

#define NWG 64
#define NB 64
#define NT 512
#define NH 512
#define BLK 512                 // elements per WG h-block
#define SREC (NWG * BLK)        // elements per step slot = 32768
#define FPAD 16                 // 64B padding stride (agent flags)

// ctrl layout (u32 indices)
#define CT_FLA0   0             // agent flags L0 (padded)   1024
#define CT_FLA1   1024          // agent flags L1 (padded)   1024
#define CT_FLB    2048          // agent inter-layer flags   1024
#define CT_FLP0   3072          // plain flags L0 (dense 64; 128B-aligned, line-exclusive)
#define CT_FLP1   3136          // plain flags L1 (dense 64)
#define CT_NONCE  3200          // 2 x 16
#define CT_PRF    3232          // 128 x 16 probe-ready (agent)
#define CT_VOTE   5280          // 128 x 16 votes (agent)
#define CT_PBUF   7328          // 128 x 16 probe values (plain)
#define CT_N      9376

typedef float f32x4 __attribute__((ext_vector_type(4)));
typedef __bf16 bf16x4 __attribute__((ext_vector_type(4)));
typedef __bf16 bf16x8 __attribute__((ext_vector_type(8)));
typedef unsigned long long u64;
typedef unsigned u32;

// ---- proven AGENT-scope (MALL) primitives ----
__device__ __forceinline__ u64 ld8a(const __bf16* p) {
    return __hip_atomic_load((const u64*)p, __ATOMIC_RELAXED, __HIP_MEMORY_SCOPE_AGENT);
}
__device__ __forceinline__ void st8a(__bf16* p, u64 v) {
    __hip_atomic_store((u64*)p, v, __ATOMIC_RELAXED, __HIP_MEMORY_SCOPE_AGENT);
}
__device__ __forceinline__ u32 ldfa(const u32* p) {
    return __hip_atomic_load(p, __ATOMIC_RELAXED, __HIP_MEMORY_SCOPE_AGENT);
}
__device__ __forceinline__ void stfa(u32* p, u32 v) {
    __hip_atomic_store(p, v, __ATOMIC_RELAXED, __HIP_MEMORY_SCOPE_AGENT);
}
// ---- plain (XCD-L2) primitives ----
__device__ __forceinline__ void inv_l1() { asm volatile("buffer_inv sc0" ::: "memory"); }
__device__ __forceinline__ u64 ld8p(const __bf16* p) { return *(const u64*)p; }
__device__ __forceinline__ void st8p(__bf16* p, u64 v) { *(u64*)p = v; }
__device__ __forceinline__ u32 ldvp(const u32* p) { return *(const volatile u32*)p; }
__device__ __forceinline__ void stvp(u32* p, u32 v) { *(volatile u32*)p = v; }

__device__ __forceinline__ unsigned short bfbits(float f) {
    __bf16 h = (__bf16)f; unsigned short u; __builtin_memcpy(&u, &h, 2); return u;
}

// agent poll: 64 padded flags, all >= tgt (wave0)
__device__ __forceinline__ void wait_flags(const u32* f, u32 tgt, int lane) {
    int g = 0;
    for (;;) {
        u32 v = ldfa(&f[lane * FPAD]);
        if (__all((int)(v >= tgt))) break;
        if (++g > (1 << 17)) break;
    }
}
// plain poll with L1 invalidate: 64 dense flags, all >= tgt (wave0)
__device__ __forceinline__ void wait_plain(const u32* f, u32 tgt, int lane) {
    int g = 0;
    for (;;) {
        inv_l1();
        u32 v = ldvp(f + lane);
        if (__all((int)(v >= tgt))) break;
        if (++g > (1 << 20)) break;
    }
}

__global__ void prep_kernel(unsigned short* hinit, unsigned short* hs1, u32* ctrl) {
    int i = blockIdx.x * blockDim.x + threadIdx.x;
    if (i < SREC) hinit[i] = 0;
    if (i < 2 * SREC) hs1[i] = 0;
    if (i < CT_N) ctrl[i] = 0;
}

// All-pairs visibility probe for one layer (64 WGs). Returns uniform verdict.
__device__ int run_probe(int layer, int wg, int tid, u32* ctrl, int* vsh) {
    const int gwg = layer * NWG + wg;
    if (tid == 0) {
        if (wg == 0) {
            u32 n = ((u32)clock64()) | 1u;
            stfa(&ctrl[CT_NONCE + layer * FPAD], n);
        }
        u32 nonce = 0; int g = 0;
        while ((nonce = ldfa(&ctrl[CT_NONCE + layer * FPAD])) == 0u)
            { if (++g > (1 << 14)) break; }
        if (nonce != 0u) {
            stvp(&ctrl[CT_PBUF + gwg * FPAD], nonce ^ ((u32)gwg * 2654435761u));
            asm volatile("s_waitcnt vmcnt(0)" ::: "memory");
            stfa(&ctrl[CT_PRF + gwg * FPAD], nonce);
        }
    }
    __syncthreads();
    // wave0: verify ALL 64 same-layer producers via inv + plain load
    if (tid < 64) {
        const int src = layer * NWG + tid;
        u32 f = 0; int g = 0;
        while ((f = ldfa(&ctrl[CT_PRF + src * FPAD])) == 0u)
            { if (++g > (1 << 15)) break; }
        int ok = 0;
        if (f != 0u) {
            inv_l1();
            u32 got = ldvp(&ctrl[CT_PBUF + src * FPAD]);
            ok = (got == (f ^ ((u32)src * 2654435761u))) ? 1 : 0;
        }
        ok = __all(ok);
        if (tid == 0) stfa(&ctrl[CT_VOTE + gwg * FPAD], ok ? 1u : 2u);
    }
    __syncthreads();
    // all WGs: AND all 128 votes (both layers -> one global mode)
    if (tid < 128) {
        u32 v = 2u; int g = 0;
        for (;;) {
            v = ldfa(&ctrl[CT_VOTE + tid * FPAD]);
            if (v != 0u) break;
            if (++g > (1 << 15)) { v = 2u; break; }
        }
        int ok = __all((int)(v == 1u));
        if ((tid & 63) == 0) vsh[tid >> 6] = ok;
    }
    __syncthreads();
    return vsh[0] & vsh[1];
}

template<int KIH, int IS_L0, bool FAST>
__device__ void layer_loop(
    char* Wl, float (*gbuf)[36], u32 (*hstage32)[4], int wg,
    const float* __restrict__ W_ih, const float* __restrict__ W_hh,
    const float* __restrict__ b_ih, const float* __restrict__ b_hh,
    const float* __restrict__ x_f32,       // L0 only
    __bf16* __restrict__ h0_all,           // [NT][SREC] step-indexed (L0 out / both read)
    const __bf16* __restrict__ hinit,      // zero block
    __bf16* __restrict__ hbuf,             // L1 parity [2][SREC]
    float* __restrict__ h_final,           // L1 only
    u32* __restrict__ ctrl)
{
    constexpr int KTOT = KIH + NH;
    constexpr int NCH_A = KIH / 32;
    constexpr int NCH_B = NH / 32;         // 16
    constexpr int ROWB = KTOT * 2;

    u32* flA_self = ctrl + (IS_L0 ? CT_FLA0 : CT_FLA1);
    const u32* flA_dep = ctrl + CT_FLA0;
    u32* flP_self = ctrl + (IS_L0 ? CT_FLP0 : CT_FLP1);
    u32* flB = ctrl + CT_FLB;

    const int tid = threadIdx.x;
    const int hcol0 = wg * 8;

    // ---- stage weight slice into LDS (bf16, row-XOR swizzle) ----
    {
        constexpr int CPR = KTOT / 8;
        for (int cid = tid; cid < 32 * CPR; cid += 256) {
            const int r = cid / CPR;
            const int k0 = (cid - r * CPR) * 8;
            const int grow = (r >> 3) * NH + hcol0 + (r & 7);
            const float* src = (k0 < KIH) ? (W_ih + (size_t)grow * KIH + k0)
                                          : (W_hh + (size_t)grow * NH + (k0 - KIH));
            union { __bf16 h[8]; uint4 u; } tmp;
            #pragma unroll
            for (int j = 0; j < 8; ++j) tmp.h[j] = (__bf16)src[j];
            const unsigned off = (unsigned)(r * ROWB) +
                (((unsigned)(2 * k0)) ^ ((unsigned)((r & 7) << 4)));
            *(uint4*)(Wl + off) = tmp.u;
        }
    }

    // epilogue mapping; biases folded; cell state in registers
    const int eb = tid >> 2, ecp = (tid & 3) * 2;
    float bI[2], bF[2], bG[2], bO[2];
    #pragma unroll
    for (int j = 0; j < 2; ++j) {
        const int c = hcol0 + ecp + j;
        bI[j] = b_ih[c] + b_hh[c];
        bF[j] = b_ih[NH + c] + b_hh[NH + c];
        bG[j] = b_ih[2 * NH + c] + b_hh[2 * NH + c];
        bO[j] = b_ih[3 * NH + c] + b_hh[3 * NH + c];
    }
    float c0 = 0.f, c1 = 0.f;
    __syncthreads();

    // MFMA mapping: 4 waves = 4 batch-tiles; each wave does BOTH gate-tiles
    const int lane = tid & 63;
    const int wid = tid >> 6;
    const int bt = wid * 16;
    const int arow = bt + (lane & 15);
    const int q4 = ((lane >> 4) & 3) * 4;
    const char* wrow0 = Wl + (lane & 15) * ROWB;
    const char* wrow1 = wrow0 + 16 * ROWB;
    const unsigned bsz = (unsigned)((lane & 7) << 4);
    const int aoff = arow * 8 + (q4 & 4);
    const int bsub = (q4 >> 3);

    auto wfragp = [&](const char* wr, int k0) -> bf16x8 {
        const bf16x4 lo = *(const bf16x4*)(wr + (((unsigned)(2 * (k0 + q4))) ^ bsz));
        const bf16x4 hi = *(const bf16x4*)(wr + (((unsigned)(2 * (k0 + 16 + q4))) ^ bsz));
        return __builtin_shufflevector(lo, hi, 0, 1, 2, 3, 4, 5, 6, 7);
    };
    auto mk8 = [&](u64 a, u64 b) -> bf16x8 {
        bf16x4 lo, hi; __builtin_memcpy(&lo, &a, 8); __builtin_memcpy(&hi, &b, 8);
        return __builtin_shufflevector(lo, hi, 0, 1, 2, 3, 4, 5, 6, 7);
    };

    // L1 fast: register prefetch of h0[t], gated by register-cached flB
    u64 ra[2 * NCH_A];
    u32 flbc = 0;
    auto gate_flb = [&](u32 tgt) {
        int g = 0;
        while (!__all((int)(flbc >= tgt))) {
            flbc = ldfa(&flB[(tid & 63) * FPAD]);
            if (++g > (1 << 17)) break;
        }
    };
    if constexpr (IS_L0 == 0 && FAST) {
        gate_flb(1u);
        #pragma unroll
        for (int kk = 0; kk < NCH_A; ++kk) {
            const __bf16* base = h0_all + (4 * kk + bsub) * BLK + aoff;
            ra[2 * kk]     = ld8a(base);
            ra[2 * kk + 1] = ld8a(base + 2 * BLK);
        }
    }

    for (int t = 0; t < NT; ++t) {
        const __bf16* __restrict__ hprev;
        __bf16* __restrict__ hout;
        if constexpr (IS_L0 != 0) {
            hprev = (t == 0) ? hinit : (h0_all + (size_t)(t - 1) * SREC);
            hout = h0_all + (size_t)t * SREC;
        } else {
            hprev = hbuf + (size_t)(t & 1) * SREC;
            hout = hbuf + (size_t)((t + 1) & 1) * SREC;
        }

        f32x4 p0a = {0,0,0,0}, p0b = {0,0,0,0};
        f32x4 p1a = {0,0,0,0}, p1b = {0,0,0,0};

        if constexpr (IS_L0 != 0) {
            // phase A from x (independent) BEFORE the wait
            const float* xb = x_f32 + ((size_t)arow * NT + t) * KIH;
            #pragma unroll
            for (int kk = 0; kk < NCH_A; ++kk) {
                const float4 lo = *(const float4*)(xb + kk * 32 + q4);
                const float4 hi = *(const float4*)(xb + kk * 32 + 16 + q4);
                const bf16x4 alo = {(__bf16)lo.x, (__bf16)lo.y, (__bf16)lo.z, (__bf16)lo.w};
                const bf16x4 ahi = {(__bf16)hi.x, (__bf16)hi.y, (__bf16)hi.z, (__bf16)hi.w};
                const bf16x8 av = __builtin_shufflevector(alo, ahi, 0, 1, 2, 3, 4, 5, 6, 7);
                f32x4& d0 = (kk & 1) ? p0b : p0a;
                d0 = __builtin_amdgcn_mfma_f32_16x16x32_bf16(av, wfragp(wrow0, kk * 32), d0, 0, 0, 0);
                f32x4& d1 = (kk & 1) ? p1b : p1a;
                d1 = __builtin_amdgcn_mfma_f32_16x16x32_bf16(av, wfragp(wrow1, kk * 32), d1, 0, 0, 0);
            }
            if (t > 0 && wid == 0) {
                if constexpr (FAST) wait_plain(flP_self, (u32)t, lane);
                else wait_flags(flA_self, (u32)t, lane);
            }
            __syncthreads();
        } else {
            if constexpr (FAST) {
                if (t > 0 && wid == 0) wait_plain(flP_self, (u32)t, lane);
                __syncthreads();
            } else {
                if (wid == 0) wait_flags(flA_dep, (u32)(t + 1), lane);
                if (wid == 1 && t > 0) wait_flags(flA_self, (u32)t, lane);
                __syncthreads();
            }
        }

        // recurrence loads
        u64 rb[2 * NCH_B];
        #pragma unroll
        for (int kk = 0; kk < NCH_B; ++kk) {
            const __bf16* base = hprev + (4 * kk + bsub) * BLK + aoff;
            if constexpr (FAST) { rb[2*kk] = ld8p(base); rb[2*kk+1] = ld8p(base + 2*BLK); }
            else                { rb[2*kk] = ld8a(base); rb[2*kk+1] = ld8a(base + 2*BLK); }
        }
        // L1: input-contribution MFMAs
        if constexpr (IS_L0 == 0) {
            if constexpr (FAST) {
                #pragma unroll
                for (int kk = 0; kk < NCH_A; ++kk) {
                    const bf16x8 av = mk8(ra[2 * kk], ra[2 * kk + 1]);
                    f32x4& d0 = (kk & 1) ? p0b : p0a;
                    d0 = __builtin_amdgcn_mfma_f32_16x16x32_bf16(av, wfragp(wrow0, kk * 32), d0, 0, 0, 0);
                    f32x4& d1 = (kk & 1) ? p1b : p1a;
                    d1 = __builtin_amdgcn_mfma_f32_16x16x32_bf16(av, wfragp(wrow1, kk * 32), d1, 0, 0, 0);
                }
            } else {
                u64 qa[2 * NCH_A];
                const __bf16* hA = h0_all + (size_t)t * SREC;
                #pragma unroll
                for (int kk = 0; kk < NCH_A; ++kk) {
                    const __bf16* base = hA + (4 * kk + bsub) * BLK + aoff;
                    qa[2 * kk]     = ld8a(base);
                    qa[2 * kk + 1] = ld8a(base + 2 * BLK);
                }
                #pragma unroll
                for (int kk = 0; kk < NCH_A; ++kk) {
                    const bf16x8 av = mk8(qa[2 * kk], qa[2 * kk + 1]);
                    f32x4& d0 = (kk & 1) ? p0b : p0a;
                    d0 = __builtin_amdgcn_mfma_f32_16x16x32_bf16(av, wfragp(wrow0, kk * 32), d0, 0, 0, 0);
                    f32x4& d1 = (kk & 1) ? p1b : p1a;
                    d1 = __builtin_amdgcn_mfma_f32_16x16x32_bf16(av, wfragp(wrow1, kk * 32), d1, 0, 0, 0);
                }
            }
        }
        #pragma unroll
        for (int kk = 0; kk < NCH_B; ++kk) {
            const bf16x8 av = mk8(rb[2 * kk], rb[2 * kk + 1]);
            f32x4& d0 = (kk & 1) ? p0b : p0a;
            d0 = __builtin_amdgcn_mfma_f32_16x16x32_bf16(av, wfragp(wrow0, KIH + kk * 32), d0, 0, 0, 0);
            f32x4& d1 = (kk & 1) ? p1b : p1a;
            d1 = __builtin_amdgcn_mfma_f32_16x16x32_bf16(av, wfragp(wrow1, KIH + kk * 32), d1, 0, 0, 0);
        }

        const f32x4 s0 = p0a + p0b, s1 = p1a + p1b;
        #pragma unroll
        for (int i = 0; i < 4; ++i) {
            gbuf[bt + ((lane >> 4) & 3) * 4 + i][lane & 15]        = s0[i];
            gbuf[bt + ((lane >> 4) & 3) * 4 + i][16 + (lane & 15)] = s1[i];
        }
        __syncthreads();

        // LSTM cell, fp32, 2 columns per thread (gate order i, f, g, o)
        {
            float hh[2]; float cc[2] = {c0, c1};
            #pragma unroll
            for (int j = 0; j < 2; ++j) {
                const int c = ecp + j;
                const float gi = gbuf[eb][c]      + bI[j];
                const float gf = gbuf[eb][8 + c]  + bF[j];
                const float gg = gbuf[eb][16 + c] + bG[j];
                const float go = gbuf[eb][24 + c] + bO[j];
                const float ii = 1.f / (1.f + __expf(-gi));
                const float ff = 1.f / (1.f + __expf(-gf));
                const float g2 = 2.f / (1.f + __expf(-2.f * gg)) - 1.f;   // tanh
                const float oo = 1.f / (1.f + __expf(-go));
                const float cn = ff * cc[j] + ii * g2;
                const float th = 2.f / (1.f + __expf(-2.f * cn)) - 1.f;
                hh[j] = oo * th;
                cc[j] = cn;
            }
            c0 = cc[0]; c1 = cc[1];
            hstage32[eb][tid & 3] = (u32)bfbits(hh[0]) | ((u32)bfbits(hh[1]) << 16);
            if constexpr (IS_L0 == 0) {
                if (t == NT - 1) {
                    h_final[(size_t)eb * NH + hcol0 + ecp]     = hh[0];
                    h_final[(size_t)eb * NH + hcol0 + ecp + 1] = hh[1];
                }
            }
        }
        __syncthreads();

        // publish this WG's contiguous 1KB block
        if (tid < 128) {
            const u64 v = ((const u64*)hstage32)[tid];
            __bf16* dst = hout + (size_t)wg * BLK + (size_t)tid * 4;
            if constexpr (FAST) {
                st8p(dst, v);                         // XCD L2 (local consumers)
                if constexpr (IS_L0 != 0) st8a(dst, v);   // MALL copy (for L1)
            } else {
                st8a(dst, v);
            }
        }
        // FAST L0: wait only the plain store (agent completes in background;
        // vmcnt in-order => at this point agent(t-1) is provably done).
        if constexpr (FAST && IS_L0 != 0) asm volatile("s_waitcnt vmcnt(1)" ::: "memory");
        else                              asm volatile("s_waitcnt vmcnt(0)" ::: "memory");
        __syncthreads();
        if (tid == 0) {
            if constexpr (FAST) {
                stvp(&flP_self[wg], (u32)(t + 1));
                if constexpr (IS_L0 != 0) stfa(&flB[wg * FPAD], (u32)t);
            } else {
                stfa(&flA_self[wg * FPAD], (u32)(t + 1));
            }
        }
        // L1 fast: prefetch next input h0[t+1] (agent; lands during next step)
        if constexpr (IS_L0 == 0 && FAST) {
            if (t < NT - 1) {
                gate_flb((u32)(t + 2));
                const __bf16* hA = h0_all + (size_t)(t + 1) * SREC;
                #pragma unroll
                for (int kk = 0; kk < NCH_A; ++kk) {
                    const __bf16* base = hA + (4 * kk + bsub) * BLK + aoff;
                    ra[2 * kk]     = ld8a(base);
                    ra[2 * kk + 1] = ld8a(base + 2 * BLK);
                }
            }
        }
    }

    if constexpr (IS_L0 != 0 && FAST) {   // final attestation: h0[NT-1] at MALL
        asm volatile("s_waitcnt vmcnt(0)" ::: "memory");
        __syncthreads();
        if (tid == 0) stfa(&flB[wg * FPAD], (u32)NT);
    }
}

__launch_bounds__(256, 2)
__global__ void lstm_kernel(
    const float* W_ih0, const float* W_hh0, const float* b_ih0, const float* b_hh0,
    const float* W_ih1, const float* W_hh1, const float* b_ih1, const float* b_hh1,
    const float* x, __bf16* h0_all, const __bf16* hinit, __bf16* hs1,
    float* hfin, u32* ctrl)
{
    __shared__ __align__(16) char Wl[32 * 2048];
    __shared__ float gbuf[64][36];
    __shared__ u32 hstage32[64][4];
    __shared__ int vsh[2];

    const int res = blockIdx.x & 7;
    if (res > 1) return;                       // dead block
    const int wg = (int)(blockIdx.x >> 3);
    const int tid = threadIdx.x;
    const int layer = res;

    const int fast = run_probe(layer, wg, tid, ctrl, vsh);

    if (layer == 0) {
        if (fast) layer_loop<128, 1, true >(Wl, gbuf, hstage32, wg,
                      W_ih0, W_hh0, b_ih0, b_hh0, x, h0_all, hinit, nullptr, nullptr, ctrl);
        else      layer_loop<128, 1, false>(Wl, gbuf, hstage32, wg,
                      W_ih0, W_hh0, b_ih0, b_hh0, x, h0_all, hinit, nullptr, nullptr, ctrl);
    } else {
        if (fast) layer_loop<512, 0, true >(Wl, gbuf, hstage32, wg,
                      W_ih1, W_hh1, b_ih1, b_hh1, nullptr, h0_all, hinit, hs1, hfin, ctrl);
        else      layer_loop<512, 0, false>(Wl, gbuf, hstage32, wg,
                      W_ih1, W_hh1, b_ih1, b_hh1, nullptr, h0_all, hinit, hs1, hfin, ctrl);
    }
}

__global__ void fc_kernel(const float* __restrict__ hfin,
                          const float* __restrict__ w_fc,
                          const float* __restrict__ b_fc,
                          float* __restrict__ out) {
    __shared__ float red[64][9];
    const int tid = threadIdx.x;
    const int b = tid >> 3, p = tid & 7;
    const int k0 = p * 64;
    float s = 0.f;
    #pragma unroll 8
    for (int k = 0; k < 64; ++k) s += hfin[(size_t)b * NH + k0 + k] * w_fc[k0 + k];
    red[b][p] = s;
    __syncthreads();
    if (p == 0) {
        float a = 0.f;
        #pragma unroll
        for (int j = 0; j < 8; ++j) a += red[b][j];
        out[b] = a + b_fc[0];
    }
}

extern "C" void kernel_launch(void* const* d_in, const int* in_sizes, int n_in,
                              void* d_out, int out_size, void* d_ws, size_t ws_size,
                              hipStream_t stream) {
    const float* x     = (const float*)d_in[0];
    const float* W_ih0 = (const float*)d_in[1];
    const float* W_hh0 = (const float*)d_in[2];
    const float* b_ih0 = (const float*)d_in[3];
    const float* b_hh0 = (const float*)d_in[4];
    const float* W_ih1 = (const float*)d_in[5];
    const float* W_hh1 = (const float*)d_in[6];
    const float* b_ih1 = (const float*)d_in[7];
    const float* b_hh1 = (const float*)d_in[8];
    const float* W_fc  = (const float*)d_in[9];
    const float* b_fc  = (const float*)d_in[10];

    // workspace layout (bytes); total ~33.95 MB (proven budget)
    char* ws = (char*)d_ws;
    __bf16* h0_all = (__bf16*)(ws);                        // 512*32768*2 = 33,554,432
    __bf16* hinit  = (__bf16*)(ws + 33554432);             // 65,536
    __bf16* hs1    = (__bf16*)(ws + 33554432 + 65536);     // 131,072
    float*  hfin   = (float*) (ws + 33554432 + 196608);    // 131,072
    u32*    ctrl   = (u32*)   (ws + 33554432 + 327680);    // 37,504

    prep_kernel<<<dim3(256), dim3(256), 0, stream>>>(
        (unsigned short*)hinit, (unsigned short*)hs1, ctrl);

    lstm_kernel<<<dim3(512), dim3(256), 0, stream>>>(
        W_ih0, W_hh0, b_ih0, b_hh0, W_ih1, W_hh1, b_ih1, b_hh1,
        x, h0_all, hinit, hs1, hfin, ctrl);

    fc_kernel<<<dim3(1), dim3(512), 0, stream>>>(hfin, W_fc, b_fc, (float*)d_out);
}